// Round 10
// baseline (127.343 us; speedup 1.0000x reference)
//
#include <hip/hip_runtime.h>
#include <hip/hip_bf16.h>

// Fused GAT value network, one block per batch element. FLOAT32 in/out.
// Rank-split GAT1 scores, row-0-only GAT2, all intermediates in LDS.
// R10 = R9 chassis (512 threads, 2 blocks/CU, async weight staging,
// max-free softmax, rcp normalize) +
//  (1) phase D eliminated: C stores exp(e); E fuses the row-sum + rcp
//      normalize into its existing full-row read (9 barriers, was 10)
//  (2) I1 v_w0 weights preloaded into registers by threads 64..213 during
//      the G+H phase (only wave 0 busy there) — I1 becomes pure FMA.

typedef float f4 __attribute__((ext_vector_type(4)));
typedef const float* cfp;

#define ASYNC_CP16(g, l) \
  __builtin_amdgcn_global_load_lds((const __attribute__((address_space(1))) void*)(g), \
                                   (__attribute__((address_space(3))) void*)(l), 16, 0, 0)

__device__ __forceinline__ f4 fma4(float s, f4 v, f4 a) { return a + s * v; }
__device__ __forceinline__ f4 max4(f4 a, f4 b) {
  f4 r;
#pragma unroll
  for (int i = 0; i < 4; ++i) r[i] = fmaxf(a[i], b[i]);
  return r;
}

#define NN 51
#define HID 64
#define XD 32
#define XS 9   // row stride of X/H1 in f4 (36 floats) — breaks 4-way bank conflicts
#define ES 52  // row stride of attention matrix in floats (13 f4, padded col)

__global__ __launch_bounds__(512, 4)
void value_net_kernel(cfp state,
                      cfp wr_w0, cfp wr_b0, cfp wr_w1, cfp wr_b1,
                      cfp wh_w0, cfp wh_b0, cfp wh_w1, cfp wh_b1,
                      cfp g0_w0, cfp g0_b0, cfp g0_w1, cfp g0_b1,
                      cfp g1_w0, cfp g1_b0, cfp g1_w1, cfp g1_b1,
                      cfp v_w0, cfp v_b0, cfp v_w1, cfp v_b1,
                      cfp v_w2, cfp v_b2,
                      float* out)
{
  __shared__ f4 sX4[52 * XS];   // X (row 51 = zero scratch)
  __shared__ f4 sH14[52 * XS];  // H1
  __shared__ f4 sU4[52 * 17];   // U(+b0) stride 68f (also: sHH scratch; W0b stage + U2)
  __shared__ f4 sV4[52 * 17];   // V (also: staged wh_w1; V2)
  __shared__ f4 sWE4[1024];     // staged W0 (4096f) (also: att matrix stride 52; head partials)
  __shared__ f4 sB04[16];
  __shared__ f4 sW14[16];
  __shared__ float sRH[64];
  __shared__ float sO[32];
  __shared__ float sM1[152];

  float* sX  = (float*)sX4;
  float* sH1 = (float*)sH14;
  float* sE  = (float*)sWE4;   // att scores alias (disjoint live range vs W0)
  float* sB0 = (float*)sB04;
  float* sW1 = (float*)sW14;
  float* sHH = (float*)sU4;    // human-hidden scratch, row stride 68
  const f4* sWh4 = (const f4*)sV4;

  const int tid = threadIdx.x;
  const int lane = tid & 63, wv = tid >> 6;
  const int b = blockIdx.x;
  cfp st = state + b * 750;

  const float gb0 = g0_b1[0];
  const float gb1 = g1_b1[0];

  float w0r[32];                // I1 weight preload (live G+H -> I1 only)
  float i1b = 0.f;

  // ---- A1: async weight staging (overlaps the hidden-layer compute below);
  //      human hidden with weights in regs + broadcast state loads;
  //      robot hidden + b0/w1 staging on wave 7.
  {
    const f4* g0w04 = (const f4*)g0_w0;          // 1024 f4: two async issues/thread
    ASYNC_CP16(g0w04 + wv * 64 + lane,        &sWE4[wv * 64]);
    ASYNC_CP16(g0w04 + 512 + wv * 64 + lane,  &sWE4[512 + wv * 64]);
    const f4* whw14 = (const f4*)wh_w1;          // 512 f4: one issue/thread
    ASYNC_CP16(whw14 + wv * 64 + lane,        ((f4*)sV4) + wv * 64);
  }
  if (tid >= 64 && tid < 64 + XS) sX4[51 * XS + (tid - 64)] = (f4){0,0,0,0};
  if (tid >= 448) {
    int t = tid - 448;
    sB0[t] = g0_b0[t];
    sW1[t] = g0_w1[t];
    float a = wr_b0[t];
#pragma unroll
    for (int k = 0; k < 9; ++k) a = fmaf(st[k], wr_w0[k * HID + t], a);
    sRH[t] = fmaxf(a, 0.f);
  }
  {
    // human hidden: thread (g = wv, t = lane); weights held in regs
    float whr[6];
#pragma unroll
    for (int k = 0; k < 6; ++k) whr[k] = wh_w0[k * HID + lane];
    float bh = wh_b0[lane];
    for (int i = wv; i < 50; i += 8) {
      cfp hp = st + i * 15 + 9;                // 6 broadcast loads per iter
      float a = bh;
#pragma unroll
      for (int k = 0; k < 6; ++k) a = fmaf(hp[k], whr[k], a);
      sHH[i * 68 + lane] = fmaxf(a, 0.f);
    }
  }
  __syncthreads();                              // drains vmcnt: async staging done

  // ---- A2: human embeddings 2-row tile (200 threads); robot emb on 448+
  if (tid < 200) {
    int ip = tid >> 3, fg = tid & 7;           // rows ip+1, ip+26
    f4 a0 = { wh_b1[fg * 4 + 0], wh_b1[fg * 4 + 1],
              wh_b1[fg * 4 + 2], wh_b1[fg * 4 + 3] };
    f4 a1 = a0;
    const f4* h0 = sU4 + ip * 17;
    const f4* h1 = sU4 + (ip + 25) * 17;
#pragma unroll 4
    for (int tg = 0; tg < 16; ++tg) {
      f4 ha = h0[tg], hb = h1[tg];
#pragma unroll
      for (int e = 0; e < 4; ++e) {
        f4 w = sWh4[(tg * 4 + e) * 8 + fg];
        a0 = fma4(ha[e], w, a0);
        a1 = fma4(hb[e], w, a1);
      }
    }
    f4 z = {0,0,0,0};
    sX4[(1 + ip) * XS + fg] = max4(a0, z);
    sX4[(26 + ip) * XS + fg] = max4(a1, z);
  } else if (tid >= 448 && tid < 448 + XD) {
    int t = tid - 448;
    float a = wr_b1[t];
#pragma unroll 8
    for (int k = 0; k < HID; ++k) a = fmaf(sRH[k], wr_w1[k * XD + t], a);
    sX[t] = fmaxf(a, 0.f);
  }
  __syncthreads();

  // ---- B: U = X@W0a + b0 ; V = X@W0b — 2-row tile, 416 tasks (rows ip, ip+26)
  if (tid < 416) {
    int ip = tid >> 4, tg = tid & 15;          // ip 0..25; row 51 = zero scratch
    f4 au0 = {0,0,0,0}, av0 = {0,0,0,0}, au1 = {0,0,0,0}, av1 = {0,0,0,0};
#pragma unroll 2
    for (int kg = 0; kg < 8; ++kg) {
      f4 x0 = sX4[ip * XS + kg];
      f4 x1 = sX4[(ip + 26) * XS + kg];
#pragma unroll
      for (int e = 0; e < 4; ++e) {
        int k = kg * 4 + e;
        f4 wU = sWE4[k * 16 + tg];
        f4 wV = sWE4[(k + 32) * 16 + tg];
        au0 = fma4(x0[e], wU, au0); av0 = fma4(x0[e], wV, av0);
        au1 = fma4(x1[e], wU, au1); av1 = fma4(x1[e], wV, av1);
      }
    }
    f4 b0v = sB04[tg];
    sU4[ip * 17 + tg] = au0 + b0v;
    sV4[ip * 17 + tg] = av0;
    sU4[(ip + 26) * 17 + tg] = au1 + b0v;     // row 51: U=b0, V=0 (safe)
    sV4[(ip + 26) * 17 + tg] = av1;
  }
  __syncthreads();

  // ---- C: pairwise scores -> UNNORMALIZED softmax numerators p = exp(e).
  //      Masked entries (j==0, i>0) and pad col 51 store 0. Max-free exp is
  //      safe (scores bounded; validated R9). E normalizes per row.
  if (tid < 338) {
    int it = tid / 13, jt = tid - (tid / 13) * 13;   // it 0..25, jt 0..12
    const f4* U0 = sU4 + it * 17;
    const f4* V0 = sV4 + jt * 17;
    f4 acc[2][4] = {};
    const f4 z = {0,0,0,0};
#pragma unroll 4
    for (int g = 0; g < 16; ++g) {
      f4 u0 = U0[g], u1 = U0[442 + g];               // rows it, it+26 (26*17=442)
      f4 vv[4] = {V0[g], V0[221 + g], V0[442 + g], V0[663 + g]};  // jt+13c
      f4 w = sW14[g];
#pragma unroll
      for (int cc = 0; cc < 4; ++cc) {
        acc[0][cc] += max4(u0 + vv[cc], z) * w;
        acc[1][cc] += max4(u1 + vv[cc], z) * w;
      }
    }
#pragma unroll
    for (int r = 0; r < 2; ++r) {
      int i = it + 26 * r;
      if (i < NN) {
#pragma unroll
        for (int cc = 0; cc < 4; ++cc) {
          int j = jt + 13 * cc;
          if (j < NN) {
            f4 A4 = acc[r][cc];
            float A = (A4[0] + A4[1]) + (A4[2] + A4[3]) + gb0;
            float e = A > 0.f ? A : 0.04f * A;
            sE[i * ES + j] = (j == 0 && i > 0) ? 0.f : __expf(e);
          } else {                              // j == 51: zero pad col
            sE[i * ES + 51] = 0.f;
          }
        }
      }
    }
  }
  __syncthreads();

  // ---- E: H1 = (p @ X) * rcp(rowsum p) — 2-row tile (208 threads), row sum
  //      fused into the existing full-row read. Waves 6-7 async-stage GAT2
  //      W0b; threads 352..383 stage b0/w1.
  if (tid < 208) {
    int ip = tid >> 3, q = tid & 7;            // rows ip, ip+26
    const f4* a0 = (const f4*)(sE + ip * ES);
    const f4* a1 = (const f4*)(sE + (ip + 26) * ES);  // row 51: finite garbage
    f4 b0 = {0,0,0,0}, b1 = {0,0,0,0};
    f4 sv0 = {0,0,0,0}, sv1 = {0,0,0,0};
    for (int jg = 0; jg < 13; ++jg) {
      f4 t0 = a0[jg], t1 = a1[jg];
      sv0 += t0;
      sv1 += t1;
#pragma unroll
      for (int e = 0; e < 4; ++e) {
        f4 x = sX4[(jg * 4 + e) * XS + q];     // row 51 zero; p col 51 zero
        b0 = fma4(t0[e], x, b0);
        b1 = fma4(t1[e], x, b1);
      }
    }
    float s0 = (sv0[0] + sv0[1]) + (sv0[2] + sv0[3]);
    float s1 = (sv1[0] + sv1[1]) + (sv1[2] + sv1[3]);
    float r0 = __builtin_amdgcn_rcpf(s0);
    float r1 = __builtin_amdgcn_rcpf(s1);      // row 51: garbage/inf, never read
    sH14[ip * XS + q] = b0 * r0;
    sH14[(ip + 26) * XS + q] = b1 * r1;
  } else if (tid >= 384) {
    // async-stage g1_w0 rows 32..63 (W0b, 512 f4) into sU4[0..512) — sU dead
    const f4* g1w = (const f4*)g1_w0 + 512;
    int wl = wv - 6;                           // 0..1
#pragma unroll
    for (int i = 0; i < 4; ++i)
      ASYNC_CP16(g1w + wl * 64 + i * 128 + lane, &sU4[wl * 64 + i * 128]);
  } else if (tid >= 352 && tid < 368) {
    sB04[tid - 352] = ((const f4*)g1_b0)[tid - 352];
  } else if (tid >= 368 && tid < 384) {
    sW14[tid - 368] = ((const f4*)g1_w1)[tid - 368];
  }
  __syncthreads();                              // drains vmcnt: W0b staged

  // ---- F2: V2 = H1@W0b — 2-row tile, 416 tasks; U2 = H1[0]@W0a + b0 (tid 416+)
  if (tid < 416) {
    int jp = tid >> 4, tg = tid & 15;          // rows jp, jp+26
    f4 av0 = {0,0,0,0}, av1 = {0,0,0,0};
#pragma unroll 2
    for (int kg = 0; kg < 8; ++kg) {
      f4 h0 = sH14[jp * XS + kg];
      f4 h1 = sH14[(jp + 26) * XS + kg];
#pragma unroll
      for (int e = 0; e < 4; ++e) {
        f4 wV = sU4[(kg * 4 + e) * 16 + tg];
        av0 = fma4(h0[e], wV, av0);
        av1 = fma4(h1[e], wV, av1);
      }
    }
    sV4[jp * 17 + tg] = av0;
    sV4[(jp + 26) * 17 + tg] = av1;            // row 51 garbage, never read
  } else if (tid < 432) {
    int tg = tid - 416;
    const f4* w0g = (const f4*)g1_w0;          // W0a rows 0..31 straight from global
    f4 au = {0,0,0,0};
#pragma unroll 2
    for (int kg = 0; kg < 8; ++kg) {
      f4 h = sH14[kg];
#pragma unroll
      for (int e = 0; e < 4; ++e) au = fma4(h[e], w0g[(kg * 4 + e) * 16 + tg], au);
    }
    sU4[512 + tg] = au + sB04[tg];
  }
  __syncthreads();

  // ---- G+H (wave 0): GAT2 row-0 scores + max-free softmax -> sE[0..50];
  //      then row 0 of (H1 + H2 + X) -> sO. Meanwhile threads 64..213
  //      preload their I1 weights into registers (global loads overlap
  //      wave 0's serial work; barrier covers them).
  if (tid < 64) {
    int j = tid;
    float e = -1e30f;
    if (j < NN) {
      f4 acc4 = {0,0,0,0};
#pragma unroll 4
      for (int g = 0; g < 16; ++g) {
        f4 u = sU4[512 + g];
        f4 v = sV4[j * 17 + g];
        f4 w = sW14[g];
        f4 z = {0,0,0,0};
        acc4 += max4(u + v, z) * w;
      }
      float acc = (acc4[0] + acc4[1]) + (acc4[2] + acc4[3]) + gb1;
      e = acc > 0.f ? acc : 0.04f * acc;
    }
    float p = __expf(e);                       // lanes >= NN: exp(-1e30) = 0
    float s = p;
#pragma unroll
    for (int o = 32; o; o >>= 1) s += __shfl_xor(s, o, 64);
    sE[j] = p * __builtin_amdgcn_rcpf(s);      // lanes >= NN write 0 (harmless pad)
    // H (same wave; wave-synchronous LDS write->read)
    if (tid < XD) {
      float a = 0.f;
      for (int jj = 0; jj < NN; ++jj) a = fmaf(sE[jj], sH1[jj * 36 + tid], a);
      sO[tid] = a + sH1[tid] + sX[tid];
    }
  } else if (tid < 214) {
    int n = tid - 64;                          // I1 output neuron
    i1b = v_b0[n];
#pragma unroll
    for (int k = 0; k < 32; ++k) w0r[k] = v_w0[k * 150 + n];
  }
  __syncthreads();

  // ---- I1: head layer 1 (32 -> 150), weights already in registers
  if (tid >= 64 && tid < 214) {
    int n = tid - 64;
    float a = i1b;
#pragma unroll 8
    for (int k = 0; k < 32; ++k) a = fmaf(sO[k], w0r[k], a);
    sM1[n] = fmaxf(a, 0.f);
  }
  __syncthreads();

  // ---- I2: head layer 2 partials, 10-way k-split (500 threads)
  if (tid < 500) {
    int kp = tid / 50, t2 = tid % 50;
    const float2* w = (const float2*)v_w1;
    float2 acc = {0.f, 0.f};
    for (int k = kp * 15; k < kp * 15 + 15; ++k) {
      float2 ww = w[k * 50 + t2];
      float xv = sM1[k];
      acc.x = fmaf(xv, ww.x, acc.x);
      acc.y = fmaf(xv, ww.y, acc.y);
    }
    ((float2*)(sE + 768 + kp * 100))[t2] = acc;
  }
  __syncthreads();

  // ---- I3: partial reduce + relu + final dot + relu, all in wave 0
  if (tid < 64) {
    float a2 = v_b1[tid];
#pragma unroll
    for (int kp = 0; kp < 10; ++kp) a2 += sE[768 + kp * 100 + tid];
    float a = fmaxf(a2, 0.f) * v_w2[tid];
    if (tid < 36) {
      float b2 = v_b1[tid + 64];
#pragma unroll
      for (int kp = 0; kp < 10; ++kp) b2 += sE[768 + kp * 100 + tid + 64];
      a = fmaf(fmaxf(b2, 0.f), v_w2[tid + 64], a);
    }
#pragma unroll
    for (int o = 32; o; o >>= 1) a += __shfl_xor(a, o, 64);
    if (tid == 0) out[b] = fmaxf(a + v_b2[0], 0.f);
  }
}

extern "C" void kernel_launch(void* const* d_in, const int* in_sizes, int n_in,
                              void* d_out, int out_size, void* d_ws, size_t ws_size,
                              hipStream_t stream) {
  cfp state = (cfp)d_in[0];
  cfp wr_w0 = (cfp)d_in[2],  wr_b0 = (cfp)d_in[3];
  cfp wr_w1 = (cfp)d_in[4],  wr_b1 = (cfp)d_in[5];
  cfp wh_w0 = (cfp)d_in[6],  wh_b0 = (cfp)d_in[7];
  cfp wh_w1 = (cfp)d_in[8],  wh_b1 = (cfp)d_in[9];
  cfp g0_w0 = (cfp)d_in[10], g0_b0 = (cfp)d_in[11];
  cfp g0_w1 = (cfp)d_in[12], g0_b1 = (cfp)d_in[13];
  cfp g1_w0 = (cfp)d_in[14], g1_b0 = (cfp)d_in[15];
  cfp g1_w1 = (cfp)d_in[16], g1_b1 = (cfp)d_in[17];
  cfp v_w0  = (cfp)d_in[18], v_b0  = (cfp)d_in[19];
  cfp v_w1  = (cfp)d_in[20], v_b1  = (cfp)d_in[21];
  cfp v_w2  = (cfp)d_in[22], v_b2  = (cfp)d_in[23];
  float* out = (float*)d_out;

  const int B = in_sizes[0] / 750;
  hipLaunchKernelGGL(value_net_kernel, dim3(B), dim3(512), 0, stream,
                     state,
                     wr_w0, wr_b0, wr_w1, wr_b1,
                     wh_w0, wh_b0, wh_w1, wh_b1,
                     g0_w0, g0_b0, g0_w1, g0_b1,
                     g1_w0, g1_b0, g1_w1, g1_b1,
                     v_w0, v_b0, v_w1, v_b1, v_w2, v_b2,
                     out);
}